// Round 6
// baseline (391.860 us; speedup 1.0000x reference)
//
#include <hip/hip_runtime.h>

typedef _Float16 f16;
typedef _Float16 f16x2 __attribute__((ext_vector_type(2)));
typedef _Float16 f16x8 __attribute__((ext_vector_type(8)));
typedef float f32x4 __attribute__((ext_vector_type(4)));

#define CIN 28
#define TT 8
#define HW 16384

// gate pre-scales folded into weights: i,f,o rows scaled by -log2e so
// E=exp2(acc)=e^{-x} and sig(x)=1/(1+E); g rows scaled by +2log2e so
// E=exp2(acc)=e^{2x} and tanh(x)=(E-1)/(E+1).
#define S_SIG  (-1.44269504088896341f)
#define S_TANH ( 2.88539008177792681f)

// workspace layout (bytes). Weight matrices stored in PACKED gate-row order:
//   pr = 16*(col>>2) + 4*(col&3) + gate
// so wave wv (0..15) owns hidden cols 4wv..4wv+3 as ONE contiguous 16-row
// MFMA tile (rows 16wv..16wv+15); within the tile, thread quad qd holds rows
// 4qd..4qd+3 = the 4 gates of hidden col 4wv+qd.
#define WS_WX    0        // f16 [256][32]  folded Wih1*W_red (+denorm, gate scale)
#define WS_WHH1  16384    // f16 [256][64]
#define WS_W21   49152    // f16 [256][64]  folded Wih2*Wc1
#define WS_WHH2  81920    // f16 [256][64]
#define WS_BX    114688   // f32 [256]  packed order
#define WS_B2    115712   // f32 [256]  packed order
#define WS_WH    116736   // f32 [64]   folded W_head*Wc2 (ORIGINAL col order)
#define WS_BH    116992   // f32 [1]

// Fused LSTM cell activation: 5 exp2 + 2 rcp (sig(f) shares the i/g rcp:
// r3 = 1/((1+Ei)(1+Eg)(1+Ef)); cn = r3*(pig*c + (Eg-1)*pf) = c/pf + (Eg-1)/pig).
__device__ __forceinline__ float lstm_act(float gi, float gf, float gg, float go,
                                          float& c) {
  const float Ei = __builtin_amdgcn_exp2f(gi);
  const float Ef = __builtin_amdgcn_exp2f(gf);
  const float Eg = __builtin_amdgcn_exp2f(gg);
  const float Eo = __builtin_amdgcn_exp2f(go);
  const float pig = (1.f + Ei) * (1.f + Eg);
  const float pf  = 1.f + Ef;
  const float r3  = __builtin_amdgcn_rcpf(pig * pf);
  const float t1  = (Eg - 1.f) * pf;
  const float cn  = r3 * __builtin_fmaf(pig, c, t1);
  c = cn;
  const float Ec  = __builtin_amdgcn_exp2f(cn * S_TANH);
  const float roc = __builtin_amdgcn_rcpf((1.f + Eo) * (1.f + Ec));
  return (Ec - 1.f) * roc;
}

// Parallel prep: 256 blocks (one per ORIGINAL gate row g) x 64 threads (k).
__global__ __launch_bounds__(64) void prep_kernel(
    const float* __restrict__ W_red, const float* __restrict__ b_red,
    const float* __restrict__ Wih1, const float* __restrict__ Whh1,
    const float* __restrict__ bih1, const float* __restrict__ bhh1,
    const float* __restrict__ Wc1,  const float* __restrict__ bc1,
    const float* __restrict__ Wih2, const float* __restrict__ Whh2,
    const float* __restrict__ bih2, const float* __restrict__ bhh2,
    const float* __restrict__ Wc2,  const float* __restrict__ bc2,
    const float* __restrict__ W_head, const float* __restrict__ b_head,
    unsigned char* __restrict__ ws)
{
  const int g = blockIdx.x;    // 0..255 ORIGINAL gate row: gate = g>>6, col = g&63
  const int k = threadIdx.x;   // 0..63
  f16* WxH   = (f16*)(ws + WS_WX);
  f16* Whh1H = (f16*)(ws + WS_WHH1);
  f16* W21H  = (f16*)(ws + WS_W21);
  f16* Whh2H = (f16*)(ws + WS_WHH2);
  float* BX  = (float*)(ws + WS_BX);
  float* B2  = (float*)(ws + WS_B2);
  float* WHp = (float*)(ws + WS_WH);
  float* BHp = (float*)(ws + WS_BH);

  const int gate = g >> 6;
  const int col  = g & 63;
  // packed destination row: one 16-row tile per 4-col wave
  const int pr = 16 * (col >> 2) + 4 * (col & 3) + gate;

  const float sc = (gate == 2) ? S_TANH : S_SIG;  // gate g uses tanh

  // Wx[g][k] = Wih1[g,:] @ W_red[:,k]  (k < CIN), + u/v denorm fold
  float wxv = 0.f;
  if (k < CIN) {
    float s = 0.f;
    for (int r = 0; r < 24; ++r) s += Wih1[g*24 + r] * W_red[r*28 + k];
    wxv = s;
  }
  const float wx11 = __shfl(wxv, 11, 64);   // pre-scale values for bias fold
  const float wx12 = __shfl(wxv, 12, 64);
  if (k == 11) wxv *= 0.15f;                // SD_U
  if (k == 12) wxv *= 0.12f;                // SD_V
  if (k < 32) WxH[pr*32 + k] = (f16)(wxv * sc);

  Whh1H[pr*64 + k] = (f16)(Whh1[g*64 + k] * sc);
  Whh2H[pr*64 + k] = (f16)(Whh2[g*64 + k] * sc);

  // W21[g][k] = Wih2[g,:] @ Wc1[:,k]   (k = ORIGINAL h1 col, unpermuted)
  {
    float s = 0.f;
    for (int m = 0; m < 64; ++m) s += Wih2[g*64 + m] * Wc1[m*64 + k];
    W21H[pr*64 + k] = (f16)(s * sc);
  }

  if (k == 0) {
    float bx = bih1[g] + bhh1[g];
    for (int r = 0; r < 24; ++r) bx += Wih1[g*24 + r] * b_red[r];
    bx += wx11 * 0.02f + wx12 * (-0.01f);   // MU_U, MU_V
    BX[pr] = bx * sc;
    float b2v = bih2[g] + bhh2[g];
    for (int m = 0; m < 64; ++m) b2v += Wih2[g*64 + m] * bc1[m];
    B2[pr] = b2v * sc;
  }
  if (g == 0) {
    float s = 0.f;
    for (int m = 0; m < 64; ++m) s += W_head[m] * Wc2[m*64 + k];
    WHp[k] = s;
    if (k == 0) {
      float s2 = b_head[0];
      for (int m = 0; m < 64; ++m) s2 += W_head[m] * bc2[m];
      BHp[0] = s2;
    }
  }
}

// 64 pixels/block, 16 waves (1024 threads); wave wv owns hidden cols
// 4wv..4wv+3 (x 4 gates) = ONE packed 16-row tile per matrix. Per-wave
// residency: 28 weight VGPRs + 8 cell-state + ~25 hot; biases live in a
// 2KB LDS table (quad-broadcast reads). __launch_bounds__(1024,8) caps the
// unified allocation at 64 regs -> 2 blocks/CU = 8 waves/SIMD (2x round 4;
// r0/r4 both plateaued at 243us stall-bound, and r3->r4 proved added waves
// convert stalls to progress).
//
// Swapped-operand MFMA: A = weights (packed rows), B = activations. Thread
// (cl,qd) of tile mb holds the 4 gates of hidden col 4wv+qd, pixel 16mb+cl
// -> one lstm_act per tile, scalar b16 h-store (banks 2-way = free).
// All MFMAs are __builtins (compiler owns every hazard).
__global__ __launch_bounds__(1024, 8)
void convlstm_main(
    const float* __restrict__ x, const unsigned char* __restrict__ ws,
    float* __restrict__ out)
{
  __shared__ __align__(16) f16 xs[2][64 * 40];       // [pixel][ch], stride 40
  __shared__ __align__(16) f16 h1buf[2][64 * 72];    // [pixel][hid], stride 72
  __shared__ __align__(16) f16 h2buf[2][64 * 72];
  __shared__ __align__(16) float biasLds[512];       // [0:256)=BX, [256:512)=B2

  const int tid  = threadIdx.x;
  const int lane = tid & 63;
  const int wv   = tid >> 6;     // wave 0..15
  const int cl   = lane & 15;    // MFMA "lane&15" (pixel within tile / A row)
  const int qd   = lane >> 4;    // MFMA quad (thread's hidden col = 4wv+qd)

  const f16* WxG   = (const f16*)(ws + WS_WX);
  const f16* Whh1G = (const f16*)(ws + WS_WHH1);
  const f16* W21G  = (const f16*)(ws + WS_W21);
  const f16* Whh2G = (const f16*)(ws + WS_WHH2);
  const float* BX  = (const float*)(ws + WS_BX);
  const float* B2  = (const float*)(ws + WS_B2);

  // ---- weight fragments: one 16-row tile per matrix ----
  f16x8 wx, whh1k0, whh1k1, w21k0, w21k1, whh2k0, whh2k1;
  {
    const int pr = wv*16 + cl;
    wx     = *(const f16x8*)(WxG   + pr*32 + qd*8);
    whh1k0 = *(const f16x8*)(Whh1G + pr*64 + qd*8);
    whh1k1 = *(const f16x8*)(Whh1G + pr*64 + 32 + qd*8);
    w21k0  = *(const f16x8*)(W21G  + pr*64 + qd*8);
    w21k1  = *(const f16x8*)(W21G  + pr*64 + 32 + qd*8);
    whh2k0 = *(const f16x8*)(Whh2G + pr*64 + qd*8);
    whh2k1 = *(const f16x8*)(Whh2G + pr*64 + 32 + qd*8);
  }

  // bias table -> LDS (read per phase as f32x4; same addr across a quad
  // group = broadcast, conflict-free)
  if (tid < 256)       biasLds[tid]       = BX[tid];
  else if (tid < 512)  biasLds[tid]       = B2[tid - 256];

  // zero t=0 h buffers (buffer 0 of each)
  {
    unsigned* z1 = (unsigned*)&h1buf[0][0];
    unsigned* z2 = (unsigned*)&h2buf[0][0];
    for (int i = tid; i < 2304; i += 1024) { z1[i] = 0u; z2[i] = 0u; }
  }

  const int gpix = blockIdx.x * 64;
  const float* xb = x + (size_t)(gpix >> 14) * (TT * CIN * HW) + (gpix & (HW - 1));

  // staging map: thread -> (pixel, channel-pair). Swizzled so a wave's 64
  // b32 writes at stride 80B land 2-way max in banks (naive 8-way).
  const int pxl = (lane & 15) + 16 * (wv & 3);       // pixel 0..63
  const int chp = 4 * (wv >> 2) + (lane >> 4);       // ch-pair 0..15 (ch=2chp)

  // stage x_0
  {
    f16x2 v;
    const int c0 = chp*2, c1 = chp*2 + 1;
    v[0] = (c0 < CIN) ? (f16)xb[c0*HW + pxl] : (f16)0.f;
    v[1] = (c1 < CIN) ? (f16)xb[c1*HW + pxl] : (f16)0.f;
    *(f16x2*)(&xs[0][pxl*40 + chp*2]) = v;
  }
  __syncthreads();

  float c1s[4], c2s[4];   // one chain per mb-tile
#pragma unroll
  for (int a = 0; a < 4; ++a) { c1s[a] = 0.f; c2s[a] = 0.f; }

  const int bofs = wv*16 + 4*qd;   // this thread's bias row base (packed)

#pragma unroll 1
  for (int t = 0; t < TT; ++t) {
    // ---- prefetch x_{t+1}, f16 at load (1 reg) ----
    f16x2 xrv;
    if (t + 1 < TT) {
      const float* xt = xb + (size_t)(t + 1) * (CIN * HW);
      const int c0 = chp*2, c1 = chp*2 + 1;
      xrv[0] = (c0 < CIN) ? (f16)xt[c0*HW + pxl] : (f16)0.f;
      xrv[1] = (c1 < CIN) ? (f16)xt[c1*HW + pxl] : (f16)0.f;
    }

    const f16* xsr = xs[t & 1];
    const f16* h1r = h1buf[t & 1];
    const f16* h2r = h2buf[t & 1];
    f16* h1w = h1buf[(t + 1) & 1];
    f16* h2w = h2buf[(t + 1) & 1];

    // ---- layer 1: gates = Whh1*h1 + Wx*x + bx (bias as C operand) ----
    const f32x4 bxq = *(const f32x4*)(&biasLds[bofs]);
#pragma unroll
    for (int mb = 0; mb < 4; ++mb) {
      const int p = 16*mb + cl;
      const f16x8 ax  = *(const f16x8*)(xsr + p*40 + qd*8);
      const f16x8 ah0 = *(const f16x8*)(h1r + p*72 + qd*8);
      const f16x8 ah1 = *(const f16x8*)(h1r + p*72 + 32 + qd*8);
      f32x4 acc;
      acc = __builtin_amdgcn_mfma_f32_16x16x32_f16(whh1k0, ah0, bxq, 0, 0, 0);
      acc = __builtin_amdgcn_mfma_f32_16x16x32_f16(whh1k1, ah1, acc, 0, 0, 0);
      acc = __builtin_amdgcn_mfma_f32_16x16x32_f16(wx,     ax,  acc, 0, 0, 0);
      const float hn = lstm_act(acc[0], acc[1], acc[2], acc[3], c1s[mb]);
      h1w[p*72 + 4*wv + qd] = (f16)hn;     // scalar b16, 2-way banks
    }
    __syncthreads();

    // ---- store prefetched x_{t+1}: overlaps layer-2 MFMA ----
    if (t + 1 < TT) {
      *(f16x2*)(xs[(t + 1) & 1] + pxl*40 + chp*2) = xrv;
    }

    // ---- layer 2: gates = W21*h1_new + Whh2*h2 + b2 (bias as C operand) ----
    const f32x4 b2q = *(const f32x4*)(&biasLds[256 + bofs]);
#pragma unroll
    for (int mb = 0; mb < 4; ++mb) {
      const int p = 16*mb + cl;
      const f16x8 an0 = *(const f16x8*)(h1w + p*72 + qd*8);
      const f16x8 an1 = *(const f16x8*)(h1w + p*72 + 32 + qd*8);
      const f16x8 a20 = *(const f16x8*)(h2r + p*72 + qd*8);
      const f16x8 a21 = *(const f16x8*)(h2r + p*72 + 32 + qd*8);
      f32x4 acc;
      acc = __builtin_amdgcn_mfma_f32_16x16x32_f16(w21k0,  an0, b2q, 0, 0, 0);
      acc = __builtin_amdgcn_mfma_f32_16x16x32_f16(w21k1,  an1, acc, 0, 0, 0);
      acc = __builtin_amdgcn_mfma_f32_16x16x32_f16(whh2k0, a20, acc, 0, 0, 0);
      acc = __builtin_amdgcn_mfma_f32_16x16x32_f16(whh2k1, a21, acc, 0, 0, 0);
      const float hn = lstm_act(acc[0], acc[1], acc[2], acc[3], c2s[mb]);
      h2w[p*72 + 4*wv + qd] = (f16)hn;
    }
    __syncthreads();
  }

  // ---- head epilogue: out[p] = bhead + sum_k h2[p][k] * wh[k] ----
  if (tid < 64) {
    const float* wh = (const float*)(ws + WS_WH);
    const f16* row = &h2buf[0][tid * 72];   // final h2 lives in buffer 0
    float s = *((const float*)(ws + WS_BH));
#pragma unroll
    for (int k = 0; k < 64; ++k) s += (float)row[k] * wh[k];
    out[gpix + tid] = s;
  }
}

extern "C" void kernel_launch(void* const* d_in, const int* in_sizes, int n_in,
                              void* d_out, int out_size, void* d_ws, size_t ws_size,
                              hipStream_t stream) {
  const float* x      = (const float*)d_in[0];
  const float* W_red  = (const float*)d_in[1];
  const float* b_red  = (const float*)d_in[2];
  const float* Wih1   = (const float*)d_in[3];
  const float* Whh1   = (const float*)d_in[4];
  const float* bih1   = (const float*)d_in[5];
  const float* bhh1   = (const float*)d_in[6];
  const float* Wc1    = (const float*)d_in[7];
  const float* bc1    = (const float*)d_in[8];
  const float* Wih2   = (const float*)d_in[9];
  const float* Whh2   = (const float*)d_in[10];
  const float* bih2   = (const float*)d_in[11];
  const float* bhh2   = (const float*)d_in[12];
  const float* Wc2    = (const float*)d_in[13];
  const float* bc2    = (const float*)d_in[14];
  const float* W_head = (const float*)d_in[15];
  const float* b_head = (const float*)d_in[16];

  prep_kernel<<<256, 64, 0, stream>>>(W_red, b_red, Wih1, Whh1, bih1, bhh1,
                                      Wc1, bc1, Wih2, Whh2, bih2, bhh2,
                                      Wc2, bc2, W_head, b_head,
                                      (unsigned char*)d_ws);
  convlstm_main<<<2048, 1024, 0, stream>>>(x, (const unsigned char*)d_ws,
                                           (float*)d_out);
}